// Round 2
// baseline (435.408 us; speedup 1.0000x reference)
//
#include <hip/hip_runtime.h>
#include <math.h>

#define B 256
#define SDIM 1024
#define TDIM 2048
#define C 128
#define NCLS 100
#define KNEG 4096
#define KNN_K 8
#define NCHUNK 16
#define KC (KNEG / NCHUNK)   // 256 rows per block
#define TINV (1.0f / 0.07f)

// ---------------------------------------------------------------------------
// Fused embed for both branches: out[b,:] = l2norm(X[b,:] @ W^T + bias)
// grid (B, 2): y=0 -> (f_s, W_es), y=1 -> (f_t, W_et). 256 thr = 4 waves,
// 32 channels per wave. Runtime S (1024 or 2048).
// ---------------------------------------------------------------------------
__global__ __launch_bounds__(256) void embed2_kernel(
    const float* __restrict__ Xs, const float* __restrict__ Ws,
    const float* __restrict__ bs, const float* __restrict__ Xt,
    const float* __restrict__ Wt, const float* __restrict__ bt,
    float* __restrict__ out_s, float* __restrict__ out_t) {
  const int which = blockIdx.y;
  const int S = which ? TDIM : SDIM;
  const float* __restrict__ X = which ? Xt : Xs;
  const float* __restrict__ W = which ? Wt : Ws;
  const float* __restrict__ bias = which ? bt : bs;
  float* __restrict__ out = which ? out_t : out_s;

  __shared__ float xrow[TDIM];
  __shared__ float ob[C];
  __shared__ float ssbuf[4];
  const int b = blockIdx.x;
  const int t = threadIdx.x;
  const int wave = t >> 6, lane = t & 63;

  const float4* xg = (const float4*)(X + (size_t)b * S);
  for (int i = t; i < S / 4; i += 256) ((float4*)xrow)[i] = xg[i];
  __syncthreads();

  const int nj = S / 256;  // float4s per lane per channel
  for (int ci = 0; ci < 32; ++ci) {
    const int c = wave * 32 + ci;
    const float4* wrow = (const float4*)(W + (size_t)c * S);
    float acc = 0.f;
    for (int j = 0; j < nj; ++j) {
      float4 w4 = wrow[lane + 64 * j];
      float4 x4 = ((const float4*)xrow)[lane + 64 * j];
      acc += w4.x * x4.x + w4.y * x4.y + w4.z * x4.z + w4.w * x4.w;
    }
#pragma unroll
    for (int off = 32; off; off >>= 1) acc += __shfl_xor(acc, off, 64);
    if (lane == 0) ob[c] = acc + bias[c];
  }
  __syncthreads();

  const float v = (t < C) ? ob[t] : 0.f;
  float ss = v * v;
#pragma unroll
  for (int off = 32; off; off >>= 1) ss += __shfl_xor(ss, off, 64);
  if (lane == 0) ssbuf[wave] = ss;
  __syncthreads();
  const float tot = ssbuf[0] + ssbuf[1] + ssbuf[2] + ssbuf[3];
  if (t < C) out[(size_t)b * C + t] = v / sqrtf(tot);
}

// ---------------------------------------------------------------------------
// knn part 1: row softmax of logits [B,NCLS] + L2 norm of softmax row.
// grid (B, 2): y=0 -> l_s, y=1 -> l_t. 128 threads.
// ---------------------------------------------------------------------------
__global__ __launch_bounds__(128) void knn_soft_kernel(
    const float* __restrict__ Ls, const float* __restrict__ Lt,
    float* __restrict__ soft_s, float* __restrict__ soft_t,
    float* __restrict__ wn_s, float* __restrict__ wn_t) {
  const int which = blockIdx.y;
  const float* L = which ? Lt : Ls;
  float* soft = which ? soft_t : soft_s;
  float* wn = which ? wn_t : wn_s;
  const int b = blockIdx.x;
  const int t = threadIdx.x;
  const int wave = t >> 6, lane = t & 63;
  __shared__ float r2[2];

  const float x = (t < NCLS) ? L[b * NCLS + t] : -INFINITY;
  float m = x;
#pragma unroll
  for (int off = 32; off; off >>= 1) m = fmaxf(m, __shfl_xor(m, off, 64));
  if (lane == 0) r2[wave] = m;
  __syncthreads();
  m = fmaxf(r2[0], r2[1]);
  __syncthreads();

  const float e = (t < NCLS) ? expf(x - m) : 0.f;
  float s = e;
#pragma unroll
  for (int off = 32; off; off >>= 1) s += __shfl_xor(s, off, 64);
  if (lane == 0) r2[wave] = s;
  __syncthreads();
  s = r2[0] + r2[1];
  __syncthreads();

  const float p = e / s;
  if (t < NCLS) soft[b * NCLS + t] = p;

  float q = p * p;
#pragma unroll
  for (int off = 32; off; off >>= 1) q += __shfl_xor(q, off, 64);
  if (lane == 0) r2[wave] = q;
  __syncthreads();
  if (t == 0) wn[b] = sqrtf(r2[0] + r2[1]);
}

// ---------------------------------------------------------------------------
// knn part 2: top-8 neighbor set per row (order irrelevant downstream; stable
// lower-index tie-break matches jax.lax.top_k). grid (B, 2), 256 threads.
// ---------------------------------------------------------------------------
__global__ __launch_bounds__(256) void knn_topk_kernel(
    const float* __restrict__ soft_s, const float* __restrict__ wn_s,
    int* __restrict__ nbr_s, const float* __restrict__ soft_t,
    const float* __restrict__ wn_t, int* __restrict__ nbr_t) {
  const int which = blockIdx.y;
  const float* __restrict__ soft = which ? soft_t : soft_s;
  const float* __restrict__ wn = which ? wn_t : wn_s;
  int* __restrict__ nbr = which ? nbr_t : nbr_s;

  const int i = blockIdx.x;
  const int j = threadIdx.x;
  __shared__ float si[NCLS];
  __shared__ float vals[B];
  __shared__ float rv[B];
  __shared__ int ri[B];

  if (j < NCLS) si[j] = soft[i * NCLS + j];
  __syncthreads();

  float dot = 0.f;
  for (int c = 0; c < NCLS; ++c) dot += si[c] * soft[j * NCLS + c];
  const float denom = fmaxf(wn[i] * wn[j], 1e-7f);
  vals[j] = (j == i) ? 1.0f : (dot / denom - 1.0f);
  __syncthreads();

  for (int r = 0; r < KNN_K; ++r) {
    rv[j] = vals[j];
    ri[j] = j;
    __syncthreads();
    for (int s = 128; s; s >>= 1) {
      if (j < s) {
        const float v2 = rv[j + s];
        const int i2 = ri[j + s];
        if (v2 > rv[j] || (v2 == rv[j] && i2 < ri[j])) { rv[j] = v2; ri[j] = i2; }
      }
      __syncthreads();
    }
    if (j == 0) {
      nbr[i * KNN_K + r] = ri[0];
      vals[ri[0]] = -INFINITY;
    }
    __syncthreads();
  }
}

// ---------------------------------------------------------------------------
// Fused TAGConv(k=1)+l2norm for BOTH branches + all four positive logits.
// one block (256 threads) per b: threads 0-127 do branch s, 128-255 branch t.
// pos[0]=ls_pos, pos[1]=lt_pos, pos[2]=gs_pos, pos[3]=gt_pos.
// Uses dot(l2norm(v),u) = dot(v,u)/||v|| so f_sgs/f_sgt never materialize.
// ---------------------------------------------------------------------------
__global__ __launch_bounds__(256) void gnn_pos_kernel(
    const float* __restrict__ f_es, const float* __restrict__ f_et,
    const int* __restrict__ nbr_s, const int* __restrict__ nbr_t,
    const float* __restrict__ W_gs, const float* __restrict__ b_gs,
    const float* __restrict__ W_gt, const float* __restrict__ b_gt,
    const float* __restrict__ mem_l, const float* __restrict__ mem_ab,
    const int* __restrict__ idx, float* __restrict__ f_gs_out,
    float* __restrict__ f_gt_out, float* __restrict__ pos) {
  const int b = blockIdx.x;
  const int t = threadIdx.x;
  const int half = t >> 7;  // 0: s-branch, 1: t-branch
  const int c = t & 127;
  const int wave = t >> 6, lane = t & 63;

  const float* __restrict__ h = half ? f_et : f_es;
  const int* __restrict__ nbr = half ? nbr_t : nbr_s;
  const float* __restrict__ Wg = half ? W_gt : W_gs;
  const float* __restrict__ bg = half ? b_gt : b_gs;

  __shared__ float hcat[2][2 * C];
  __shared__ float gbuf[2][C];
  __shared__ float red[4];
  __shared__ float r26[2][6];

  float agg = 0.f;
#pragma unroll
  for (int j = 0; j < KNN_K; ++j)
    agg += h[(size_t)nbr[b * KNN_K + j] * C + c];
  hcat[half][c] = h[(size_t)b * C + c];
  hcat[half][C + c] = agg * (1.0f / KNN_K);
  __syncthreads();

  float acc = bg[c];
  for (int k = 0; k < 2 * C; ++k) acc += hcat[half][k] * Wg[k * C + c];

  float ss = acc * acc;
#pragma unroll
  for (int off = 32; off; off >>= 1) ss += __shfl_xor(ss, off, 64);
  if (lane == 0) red[wave] = ss;
  __syncthreads();
  const float g = acc / sqrtf(red[half * 2] + red[half * 2 + 1]);
  gbuf[half][c] = g;
  (half ? f_gt_out : f_gs_out)[(size_t)b * C + c] = g;
  __syncthreads();

  // pos epilogue on threads 0-127 (waves 0,1)
  if (half == 0) {
    const int id = idx[b];
    const float ml = mem_l[(size_t)id * C + c];
    const float mab = mem_ab[(size_t)id * C + c];
    const float es = f_es[(size_t)b * C + c];
    const float et = f_et[(size_t)b * C + c];
    const float gs = gbuf[0][c];
    const float gt = gbuf[1][c];
    const float sgs = 0.75f * ml + 0.25f * gs;
    const float sgt = 0.75f * mab + 0.25f * gt;

    float v6[6] = {sgs * sgs, sgt * sgt, mab * es, ml * et, sgt * gs, sgs * gt};
#pragma unroll
    for (int q = 0; q < 6; ++q) {
      float v = v6[q];
#pragma unroll
      for (int off = 32; off; off >>= 1) v += __shfl_xor(v, off, 64);
      if (lane == 0) r26[wave][q] = v;
    }
  }
  __syncthreads();
  if (t == 0) {
    const float ss_gs = r26[0][0] + r26[1][0];
    const float ss_gt = r26[0][1] + r26[1][1];
    pos[0 * B + b] = r26[0][2] + r26[1][2];                  // ls_pos
    pos[1 * B + b] = r26[0][3] + r26[1][3];                  // lt_pos
    pos[2 * B + b] = (r26[0][4] + r26[1][4]) / sqrtf(ss_gt); // gs_pos
    pos[3 * B + b] = (r26[0][5] + r26[1][5]) / sqrtf(ss_gs); // gt_pos
  }
}

// ---------------------------------------------------------------------------
// Heavy fused gather kernel, 16-lanes-per-row layout. grid (B, NCHUNK, 2).
// bank 0: mem_l x (f_es -> loss0, f_gs -> loss2)
// bank 1: mem_ab x (f_et -> loss1, f_gt -> loss3)
// Each 16-lane group owns one gathered row per iteration: loads are two
// contiguous 256B segments (fully-used cache lines), query fragments live in
// 16 registers (zero LDS traffic in the loop). Deterministic reduction.
// ---------------------------------------------------------------------------
__global__ __launch_bounds__(256) void neg_partial_kernel(
    const float* __restrict__ mem_l, const float* __restrict__ mem_ab,
    const int* __restrict__ cidx, const float* __restrict__ f_es,
    const float* __restrict__ f_et, const float* __restrict__ f_gs,
    const float* __restrict__ f_gt, float* __restrict__ partial) {
  const int b = blockIdx.x;
  const int chunk = blockIdx.y;
  const int bank = blockIdx.z;
  const float* __restrict__ mem = bank ? mem_ab : mem_l;
  const float* __restrict__ f1 = bank ? f_et : f_es;
  const float* __restrict__ f2 = bank ? f_gt : f_gs;
  const int t = threadIdx.x;
  const int wave = t >> 6, lane = t & 63;
  const int grp = t >> 4;   // 0..15
  const int lig = t & 15;   // lane in 16-lane group

  __shared__ int rows[KC];
  __shared__ float rbuf[4][2];

  rows[t] = cidx[(size_t)b * KNEG + chunk * KC + t];

  // query fragments: this lane's fixed 8 elements of each vector
  const float4 x1lo = ((const float4*)f1)[b * 32 + lig];
  const float4 x1hi = ((const float4*)f1)[b * 32 + lig + 16];
  const float4 x2lo = ((const float4*)f2)[b * 32 + lig];
  const float4 x2hi = ((const float4*)f2)[b * 32 + lig + 16];
  __syncthreads();

  float s1 = 0.f, s2 = 0.f;
#pragma unroll
  for (int it = 0; it < 16; ++it) {
    const int row = rows[grp * 16 + it];  // uniform in group -> LDS broadcast
    const float4* __restrict__ r = (const float4*)(mem + (size_t)row * C);
    const float4 vlo = r[lig];
    const float4 vhi = r[lig + 16];
    float a1 = vlo.x * x1lo.x + vlo.y * x1lo.y + vlo.z * x1lo.z + vlo.w * x1lo.w
             + vhi.x * x1hi.x + vhi.y * x1hi.y + vhi.z * x1hi.z + vhi.w * x1hi.w;
    float a2 = vlo.x * x2lo.x + vlo.y * x2lo.y + vlo.z * x2lo.z + vlo.w * x2lo.w
             + vhi.x * x2hi.x + vhi.y * x2hi.y + vhi.z * x2hi.z + vhi.w * x2hi.w;
#pragma unroll
    for (int off = 8; off; off >>= 1) {
      a1 += __shfl_xor(a1, off, 64);
      a2 += __shfl_xor(a2, off, 64);
    }
    // all 16 lanes of the group now hold the full dot
    s1 += __expf(a1 * TINV);
    s2 += __expf(a2 * TINV);
  }
  // combine the 4 groups of this wave: values are replicated within groups,
  // so xor-32 then xor-16 leaves lane 0 with s(g0)+s(g2)+s(g1)+s(g3).
  s1 += __shfl_xor(s1, 32, 64);
  s1 += __shfl_xor(s1, 16, 64);
  s2 += __shfl_xor(s2, 32, 64);
  s2 += __shfl_xor(s2, 16, 64);
  if (lane == 0) { rbuf[wave][0] = s1; rbuf[wave][1] = s2; }
  __syncthreads();
  if (t == 0) {
    const float v1 = rbuf[0][0] + rbuf[1][0] + rbuf[2][0] + rbuf[3][0];
    const float v2 = rbuf[0][1] + rbuf[1][1] + rbuf[2][1] + rbuf[3][1];
    partial[((size_t)bank * B + b) * NCHUNK + chunk] = v1;
    partial[((size_t)(bank + 2) * B + b) * NCHUNK + chunk] = v2;
  }
}

// ---------------------------------------------------------------------------
// Final: loss = sum_l mean_b( log(exp(pos/T) + sum_k exp(neg/T)) - pos/T )
// ---------------------------------------------------------------------------
__global__ __launch_bounds__(256) void loss_kernel(
    const float* __restrict__ partial, const float* __restrict__ pos,
    float* __restrict__ out) {
  const int b = threadIdx.x;
  const int wave = b >> 6, lane = b & 63;
  __shared__ float rb[4];
  float contrib = 0.f;
#pragma unroll
  for (int l = 0; l < 4; ++l) {
    const float p = pos[l * B + b] * TINV;
    float s = expf(p);
    for (int ch = 0; ch < NCHUNK; ++ch)
      s += partial[((size_t)l * B + b) * NCHUNK + ch];
    contrib += logf(s) - p;
  }
#pragma unroll
  for (int off = 32; off; off >>= 1) contrib += __shfl_xor(contrib, off, 64);
  if (lane == 0) rb[wave] = contrib;
  __syncthreads();
  if (b == 0) out[0] = (rb[0] + rb[1] + rb[2] + rb[3]) * (1.0f / B);
}

// ---------------------------------------------------------------------------
extern "C" void kernel_launch(void* const* d_in, const int* in_sizes, int n_in,
                              void* d_out, int out_size, void* d_ws,
                              size_t ws_size, hipStream_t stream) {
  // 0 epoch, 1 f_s, 2 l_s, 3 f_t, 4 l_t, 5 idx, 6 contrast_idx,
  // 7 W_es, 8 b_es, 9 W_et, 10 b_et, 11 W_gs, 12 b_gs, 13 W_gt, 14 b_gt,
  // 15 memory_l, 16 memory_ab
  const float* f_s = (const float*)d_in[1];
  const float* l_s = (const float*)d_in[2];
  const float* f_t = (const float*)d_in[3];
  const float* l_t = (const float*)d_in[4];
  const int* idx = (const int*)d_in[5];
  const int* cidx = (const int*)d_in[6];
  const float* W_es = (const float*)d_in[7];
  const float* b_es = (const float*)d_in[8];
  const float* W_et = (const float*)d_in[9];
  const float* b_et = (const float*)d_in[10];
  const float* W_gs = (const float*)d_in[11];
  const float* b_gs = (const float*)d_in[12];
  const float* W_gt = (const float*)d_in[13];
  const float* b_gt = (const float*)d_in[14];
  const float* mem_l = (const float*)d_in[15];
  const float* mem_ab = (const float*)d_in[16];

  char* w = (char*)d_ws;
  float* ws_f_es = (float*)w;    w += B * C * sizeof(float);
  float* ws_f_et = (float*)w;    w += B * C * sizeof(float);
  float* ws_f_gs = (float*)w;    w += B * C * sizeof(float);
  float* ws_f_gt = (float*)w;    w += B * C * sizeof(float);
  float* ws_soft_s = (float*)w;  w += B * NCLS * sizeof(float);
  float* ws_soft_t = (float*)w;  w += B * NCLS * sizeof(float);
  float* ws_wn_s = (float*)w;    w += B * sizeof(float);
  float* ws_wn_t = (float*)w;    w += B * sizeof(float);
  int* ws_nbr_s = (int*)w;       w += B * KNN_K * sizeof(int);
  int* ws_nbr_t = (int*)w;       w += B * KNN_K * sizeof(int);
  float* ws_pos = (float*)w;     w += 4 * B * sizeof(float);
  float* ws_partial = (float*)w; w += 4 * B * NCHUNK * sizeof(float);

  embed2_kernel<<<dim3(B, 2), 256, 0, stream>>>(f_s, W_es, b_es, f_t, W_et,
                                                b_et, ws_f_es, ws_f_et);

  knn_soft_kernel<<<dim3(B, 2), 128, 0, stream>>>(l_s, l_t, ws_soft_s,
                                                  ws_soft_t, ws_wn_s, ws_wn_t);

  knn_topk_kernel<<<dim3(B, 2), 256, 0, stream>>>(ws_soft_s, ws_wn_s, ws_nbr_s,
                                                  ws_soft_t, ws_wn_t, ws_nbr_t);

  gnn_pos_kernel<<<B, 256, 0, stream>>>(ws_f_es, ws_f_et, ws_nbr_s, ws_nbr_t,
                                        W_gs, b_gs, W_gt, b_gt, mem_l, mem_ab,
                                        idx, ws_f_gs, ws_f_gt, ws_pos);

  neg_partial_kernel<<<dim3(B, NCHUNK, 2), 256, 0, stream>>>(
      mem_l, mem_ab, cidx, ws_f_es, ws_f_et, ws_f_gs, ws_f_gt, ws_partial);

  loss_kernel<<<1, 256, 0, stream>>>(ws_partial, ws_pos, (float*)d_out);
}

// Round 4
// 420.155 us; speedup vs baseline: 1.0363x; 1.0363x over previous
//
#include <hip/hip_runtime.h>
#include <math.h>

#define B 256
#define SDIM 1024
#define TDIM 2048
#define C 128
#define NCLS 100
#define KNEG 4096
#define KNN_K 8
#define NCHUNK 16
#define KC (KNEG / NCHUNK)   // 256 rows per block
#define TINV (1.0f / 0.07f)

// ---------------------------------------------------------------------------
// DPP helpers: cross-lane sums on the VALU pipe (no DS-pipe swizzles).
// sum16: all 16 lanes of each aligned 16-lane row end with the row's sum.
// ---------------------------------------------------------------------------
template <int CTRL>
__device__ __forceinline__ float dpp_add(float v) {
  const int x = __builtin_amdgcn_update_dpp(0, __float_as_int(v), CTRL, 0xF, 0xF, true);
  return v + __int_as_float(x);
}
__device__ __forceinline__ float sum16(float v) {
  v = dpp_add<0xB1>(v);   // quad_perm [1,0,3,2]
  v = dpp_add<0x4E>(v);   // quad_perm [2,3,0,1]
  v = dpp_add<0x141>(v);  // row_half_mirror
  v = dpp_add<0x140>(v);  // row_mirror
  return v;
}
__device__ __forceinline__ float wave_sum64(float v) {
  v = sum16(v);
  v += __shfl_xor(v, 16, 64);
  v += __shfl_xor(v, 32, 64);
  return v;
}
__device__ __forceinline__ float dot4(float4 a, float4 b) {
  return a.x * b.x + a.y * b.y + a.z * b.z + a.w * b.w;
}

// ---------------------------------------------------------------------------
// Fused embed, 4 batch rows per block: out[b,:] = l2norm(X[b,:] @ W^T + bias)
// grid (B/4, 2): y=0 -> (f_s,W_es), y=1 -> (f_t,W_et). 256 thr = 4 waves.
// Each wave owns 32 channels; each W fragment is loaded ONCE and used for all
// 4 rows (4x W-traffic reduction + 4 independent FMA/reduce chains for ILP).
// ---------------------------------------------------------------------------
__global__ __launch_bounds__(256) void embed2_kernel(
    const float* __restrict__ Xs, const float* __restrict__ Ws,
    const float* __restrict__ bs, const float* __restrict__ Xt,
    const float* __restrict__ Wt, const float* __restrict__ bt,
    float* __restrict__ out_s, float* __restrict__ out_t) {
  const int which = blockIdx.y;
  const int S = which ? TDIM : SDIM;
  const float* __restrict__ X = which ? Xt : Xs;
  const float* __restrict__ W = which ? Wt : Ws;
  const float* __restrict__ bias = which ? bt : bs;
  float* __restrict__ out = which ? out_t : out_s;

  __shared__ float xrow[4 * TDIM];
  __shared__ float ob[4][C];
  const int b4 = blockIdx.x * 4;
  const int t = threadIdx.x;
  const int wave = t >> 6, lane = t & 63;

  // rows b4..b4+3 are contiguous in X: one linear float4 copy of S float4s
  const float4* xg = (const float4*)(X + (size_t)b4 * S);
  for (int i = t; i < S; i += 256) ((float4*)xrow)[i] = xg[i];
  __syncthreads();

  const int nj = S / 256;  // float4s per lane per channel
  const int sq = S / 4;    // float4s per row
  for (int ci = 0; ci < 32; ++ci) {
    const int c = wave * 32 + ci;
    const float4* wrow = (const float4*)(W + (size_t)c * S);
    float a0 = 0.f, a1 = 0.f, a2 = 0.f, a3 = 0.f;
    for (int j = 0; j < nj; ++j) {
      const float4 w4 = wrow[lane + 64 * j];
      a0 += dot4(w4, ((const float4*)xrow)[0 * sq + lane + 64 * j]);
      a1 += dot4(w4, ((const float4*)xrow)[1 * sq + lane + 64 * j]);
      a2 += dot4(w4, ((const float4*)xrow)[2 * sq + lane + 64 * j]);
      a3 += dot4(w4, ((const float4*)xrow)[3 * sq + lane + 64 * j]);
    }
    a0 = wave_sum64(a0); a1 = wave_sum64(a1);
    a2 = wave_sum64(a2); a3 = wave_sum64(a3);
    if (lane == 0) {
      const float bb = bias[c];
      ob[0][c] = a0 + bb; ob[1][c] = a1 + bb;
      ob[2][c] = a2 + bb; ob[3][c] = a3 + bb;
    }
  }
  __syncthreads();

  // wave w normalizes and writes row b4+w (2 elements per lane)
  const float v1 = ob[wave][lane];
  const float v2 = ob[wave][lane + 64];
  const float ss = wave_sum64(v1 * v1 + v2 * v2);
  const float inv = 1.0f / sqrtf(ss);
  out[(size_t)(b4 + wave) * C + lane] = v1 * inv;
  out[(size_t)(b4 + wave) * C + lane + 64] = v2 * inv;
}

// ---------------------------------------------------------------------------
// knn part 1: row softmax of logits [B,NCLS] + L2 norm of softmax row.
// grid (B, 2): y=0 -> l_s, y=1 -> l_t. 128 threads.
// ---------------------------------------------------------------------------
__global__ __launch_bounds__(128) void knn_soft_kernel(
    const float* __restrict__ Ls, const float* __restrict__ Lt,
    float* __restrict__ soft_s, float* __restrict__ soft_t,
    float* __restrict__ wn_s, float* __restrict__ wn_t) {
  const int which = blockIdx.y;
  const float* L = which ? Lt : Ls;
  float* soft = which ? soft_t : soft_s;
  float* wn = which ? wn_t : wn_s;
  const int b = blockIdx.x;
  const int t = threadIdx.x;
  const int wave = t >> 6, lane = t & 63;
  __shared__ float r2[2];

  const float x = (t < NCLS) ? L[b * NCLS + t] : -INFINITY;
  float m = x;
#pragma unroll
  for (int off = 32; off; off >>= 1) m = fmaxf(m, __shfl_xor(m, off, 64));
  if (lane == 0) r2[wave] = m;
  __syncthreads();
  m = fmaxf(r2[0], r2[1]);
  __syncthreads();

  const float e = (t < NCLS) ? expf(x - m) : 0.f;
  float s = e;
#pragma unroll
  for (int off = 32; off; off >>= 1) s += __shfl_xor(s, off, 64);
  if (lane == 0) r2[wave] = s;
  __syncthreads();
  s = r2[0] + r2[1];
  __syncthreads();

  const float p = e / s;
  if (t < NCLS) soft[b * NCLS + t] = p;

  float q = p * p;
#pragma unroll
  for (int off = 32; off; off >>= 1) q += __shfl_xor(q, off, 64);
  if (lane == 0) r2[wave] = q;
  __syncthreads();
  if (t == 0) wn[b] = sqrtf(r2[0] + r2[1]);
}

// ---------------------------------------------------------------------------
// knn part 2: top-8 neighbor set per row. grid (B, 2), 256 threads.
// Phase 1: 256 threads compute the 256 neg-distances (float4 dots).
// Phase 2: wave 0 does 8 rounds of shuffle argmax (zero extra barriers).
// Tie-break lower index == jax.lax.top_k. Order irrelevant downstream (mean).
// ---------------------------------------------------------------------------
__global__ __launch_bounds__(256) void knn_topk_kernel(
    const float* __restrict__ soft_s, const float* __restrict__ wn_s,
    int* __restrict__ nbr_s, const float* __restrict__ soft_t,
    const float* __restrict__ wn_t, int* __restrict__ nbr_t) {
  const int which = blockIdx.y;
  const float* __restrict__ soft = which ? soft_t : soft_s;
  const float* __restrict__ wn = which ? wn_t : wn_s;
  int* __restrict__ nbr = which ? nbr_t : nbr_s;

  const int i = blockIdx.x;
  const int j = threadIdx.x;
  __shared__ float si[NCLS];
  __shared__ float vals[B];

  if (j < NCLS) si[j] = soft[i * NCLS + j];
  __syncthreads();

  float dot = 0.f;
  const float4* sj4 = (const float4*)(soft + j * NCLS);
#pragma unroll
  for (int c = 0; c < NCLS / 4; ++c) dot += dot4(((const float4*)si)[c], sj4[c]);
  const float denom = fmaxf(wn[i] * wn[j], 1e-7f);
  vals[j] = (j == i) ? 1.0f : (dot / denom - 1.0f);
  __syncthreads();

  if (j < 64) {
    float v0 = vals[j], v1 = vals[j + 64], v2 = vals[j + 128], v3 = vals[j + 192];
    for (int r = 0; r < KNN_K; ++r) {
      float bv = v0; int bi = j;
      if (v1 > bv) { bv = v1; bi = j + 64; }
      if (v2 > bv) { bv = v2; bi = j + 128; }
      if (v3 > bv) { bv = v3; bi = j + 192; }
#pragma unroll
      for (int off = 1; off < 64; off <<= 1) {
        const float ov = __shfl_xor(bv, off, 64);
        const int oi = __shfl_xor(bi, off, 64);
        if (ov > bv || (ov == bv && oi < bi)) { bv = ov; bi = oi; }
      }
      if (j == 0) nbr[i * KNN_K + r] = bi;
      if (j == (bi & 63)) {
        const int q = bi >> 6;
        if (q == 0) v0 = -INFINITY;
        else if (q == 1) v1 = -INFINITY;
        else if (q == 2) v2 = -INFINITY;
        else v3 = -INFINITY;
      }
    }
  }
}

// ---------------------------------------------------------------------------
// Fused TAGConv(k=1)+l2norm for BOTH branches + all four positive logits.
// one block (256 threads) per b: threads 0-127 branch s, 128-255 branch t.
// ---------------------------------------------------------------------------
__global__ __launch_bounds__(256) void gnn_pos_kernel(
    const float* __restrict__ f_es, const float* __restrict__ f_et,
    const int* __restrict__ nbr_s, const int* __restrict__ nbr_t,
    const float* __restrict__ W_gs, const float* __restrict__ b_gs,
    const float* __restrict__ W_gt, const float* __restrict__ b_gt,
    const float* __restrict__ mem_l, const float* __restrict__ mem_ab,
    const int* __restrict__ idx, float* __restrict__ f_gs_out,
    float* __restrict__ f_gt_out, float* __restrict__ pos) {
  const int b = blockIdx.x;
  const int t = threadIdx.x;
  const int half = t >> 7;
  const int c = t & 127;
  const int wave = t >> 6, lane = t & 63;

  const float* __restrict__ h = half ? f_et : f_es;
  const int* __restrict__ nbr = half ? nbr_t : nbr_s;
  const float* __restrict__ Wg = half ? W_gt : W_gs;
  const float* __restrict__ bg = half ? b_gt : b_gs;

  __shared__ float hcat[2][2 * C];
  __shared__ float gbuf[2][C];
  __shared__ float red[4];
  __shared__ float r26[2][6];

  float agg = 0.f;
#pragma unroll
  for (int j = 0; j < KNN_K; ++j)
    agg += h[(size_t)nbr[b * KNN_K + j] * C + c];
  hcat[half][c] = h[(size_t)b * C + c];
  hcat[half][C + c] = agg * (1.0f / KNN_K);
  __syncthreads();

  float acc = bg[c];
  for (int k = 0; k < 2 * C; ++k) acc += hcat[half][k] * Wg[k * C + c];

  float ss = acc * acc;
#pragma unroll
  for (int off = 32; off; off >>= 1) ss += __shfl_xor(ss, off, 64);
  if (lane == 0) red[wave] = ss;
  __syncthreads();
  const float g = acc / sqrtf(red[half * 2] + red[half * 2 + 1]);
  gbuf[half][c] = g;
  (half ? f_gt_out : f_gs_out)[(size_t)b * C + c] = g;
  __syncthreads();

  if (half == 0) {
    const int id = idx[b];
    const float ml = mem_l[(size_t)id * C + c];
    const float mab = mem_ab[(size_t)id * C + c];
    const float es = f_es[(size_t)b * C + c];
    const float et = f_et[(size_t)b * C + c];
    const float gs = gbuf[0][c];
    const float gt = gbuf[1][c];
    const float sgs = 0.75f * ml + 0.25f * gs;
    const float sgt = 0.75f * mab + 0.25f * gt;

    float v6[6] = {sgs * sgs, sgt * sgt, mab * es, ml * et, sgt * gs, sgs * gt};
#pragma unroll
    for (int q = 0; q < 6; ++q) {
      float v = v6[q];
#pragma unroll
      for (int off = 32; off; off >>= 1) v += __shfl_xor(v, off, 64);
      if (lane == 0) r26[wave][q] = v;
    }
  }
  __syncthreads();
  if (t == 0) {
    const float ss_gs = r26[0][0] + r26[1][0];
    const float ss_gt = r26[0][1] + r26[1][1];
    pos[0 * B + b] = r26[0][2] + r26[1][2];                  // ls_pos
    pos[1 * B + b] = r26[0][3] + r26[1][3];                  // lt_pos
    pos[2 * B + b] = (r26[0][4] + r26[1][4]) / sqrtf(ss_gt); // gs_pos
    pos[3 * B + b] = (r26[0][5] + r26[1][5]) / sqrtf(ss_gs); // gt_pos
  }
}

// ---------------------------------------------------------------------------
// Heavy fused gather kernel. grid (B, NCHUNK, 2). 16 lanes per gathered row.
// (1) DPP-based 16-lane reduction on the VALU pipe (was an 8-deep serial
// DS-swizzle chain = the measured latency bottleneck),
// (2) U=2 software pipeline: loads for the next row-pair issue before the
// current pair's reduce chain -> 4 float4 loads in flight per wave.
// ---------------------------------------------------------------------------
__global__ __launch_bounds__(256) void neg_partial_kernel(
    const float* __restrict__ mem_l, const float* __restrict__ mem_ab,
    const int* __restrict__ cidx, const float* __restrict__ f_es,
    const float* __restrict__ f_et, const float* __restrict__ f_gs,
    const float* __restrict__ f_gt, float* __restrict__ partial) {
  const int b = blockIdx.x;
  const int chunk = blockIdx.y;
  const int bank = blockIdx.z;
  const float* __restrict__ mem = bank ? mem_ab : mem_l;
  const float* __restrict__ f1 = bank ? f_et : f_es;
  const float* __restrict__ f2 = bank ? f_gt : f_gs;
  const int t = threadIdx.x;
  const int wave = t >> 6, lane = t & 63;
  const int grp = t >> 4;   // 0..15
  const int lig = t & 15;   // lane in 16-lane group

  __shared__ int rows[KC];
  __shared__ float rbuf[4][2];

  rows[t] = cidx[(size_t)b * KNEG + chunk * KC + t];

  const float4 x1lo = ((const float4*)f1)[b * 32 + lig];
  const float4 x1hi = ((const float4*)f1)[b * 32 + lig + 16];
  const float4 x2lo = ((const float4*)f2)[b * 32 + lig];
  const float4 x2hi = ((const float4*)f2)[b * 32 + lig + 16];
  __syncthreads();

  // prologue: loads for row pair 0
  const float4* pa = (const float4*)(mem + ((size_t)rows[grp * 16 + 0] << 7));
  const float4* pb = (const float4*)(mem + ((size_t)rows[grp * 16 + 1] << 7));
  float4 alo = pa[lig], ahi = pa[lig + 16];
  float4 blo = pb[lig], bhi = pb[lig + 16];

  float s1 = 0.f, s2 = 0.f;
  for (int it = 0; it < 16; it += 2) {
    const float4 calo = alo, cahi = ahi, cblo = blo, cbhi = bhi;
    if (it + 2 < 16) {  // prefetch next pair before the reduce chain
      const float4* na = (const float4*)(mem + ((size_t)rows[grp * 16 + it + 2] << 7));
      const float4* nb = (const float4*)(mem + ((size_t)rows[grp * 16 + it + 3] << 7));
      alo = na[lig]; ahi = na[lig + 16];
      blo = nb[lig]; bhi = nb[lig + 16];
    }
    float d1a = dot4(calo, x1lo) + dot4(cahi, x1hi);
    float d2a = dot4(calo, x2lo) + dot4(cahi, x2hi);
    float d1b = dot4(cblo, x1lo) + dot4(cbhi, x1hi);
    float d2b = dot4(cblo, x2lo) + dot4(cbhi, x2hi);
    d1a = sum16(d1a); d2a = sum16(d2a);
    d1b = sum16(d1b); d2b = sum16(d2b);
    s1 += __expf(d1a * TINV) + __expf(d1b * TINV);
    s2 += __expf(d2a * TINV) + __expf(d2b * TINV);
  }
  // combine the 4 groups of this wave (values replicated within each group)
  s1 += __shfl_xor(s1, 32, 64);
  s1 += __shfl_xor(s1, 16, 64);
  s2 += __shfl_xor(s2, 32, 64);
  s2 += __shfl_xor(s2, 16, 64);
  if (lane == 0) { rbuf[wave][0] = s1; rbuf[wave][1] = s2; }
  __syncthreads();
  if (t == 0) {
    const float v1 = rbuf[0][0] + rbuf[1][0] + rbuf[2][0] + rbuf[3][0];
    const float v2 = rbuf[0][1] + rbuf[1][1] + rbuf[2][1] + rbuf[3][1];
    partial[((size_t)bank * B + b) * NCHUNK + chunk] = v1;
    partial[((size_t)(bank + 2) * B + b) * NCHUNK + chunk] = v2;
  }
}

// ---------------------------------------------------------------------------
// Final: loss = sum_l mean_b( log(exp(pos/T) + sum_k exp(neg/T)) - pos/T )
// ---------------------------------------------------------------------------
__global__ __launch_bounds__(256) void loss_kernel(
    const float* __restrict__ partial, const float* __restrict__ pos,
    float* __restrict__ out) {
  const int b = threadIdx.x;
  const int wave = b >> 6, lane = b & 63;
  __shared__ float rb[4];
  float contrib = 0.f;
#pragma unroll
  for (int l = 0; l < 4; ++l) {
    const float p = pos[l * B + b] * TINV;
    float s = expf(p);
    for (int ch = 0; ch < NCHUNK; ++ch)
      s += partial[((size_t)l * B + b) * NCHUNK + ch];
    contrib += logf(s) - p;
  }
#pragma unroll
  for (int off = 32; off; off >>= 1) contrib += __shfl_xor(contrib, off, 64);
  if (lane == 0) rb[wave] = contrib;
  __syncthreads();
  if (b == 0) out[0] = (rb[0] + rb[1] + rb[2] + rb[3]) * (1.0f / B);
}

// ---------------------------------------------------------------------------
extern "C" void kernel_launch(void* const* d_in, const int* in_sizes, int n_in,
                              void* d_out, int out_size, void* d_ws,
                              size_t ws_size, hipStream_t stream) {
  const float* f_s = (const float*)d_in[1];
  const float* l_s = (const float*)d_in[2];
  const float* f_t = (const float*)d_in[3];
  const float* l_t = (const float*)d_in[4];
  const int* idx = (const int*)d_in[5];
  const int* cidx = (const int*)d_in[6];
  const float* W_es = (const float*)d_in[7];
  const float* b_es = (const float*)d_in[8];
  const float* W_et = (const float*)d_in[9];
  const float* b_et = (const float*)d_in[10];
  const float* W_gs = (const float*)d_in[11];
  const float* b_gs = (const float*)d_in[12];
  const float* W_gt = (const float*)d_in[13];
  const float* b_gt = (const float*)d_in[14];
  const float* mem_l = (const float*)d_in[15];
  const float* mem_ab = (const float*)d_in[16];

  char* w = (char*)d_ws;
  float* ws_f_es = (float*)w;    w += B * C * sizeof(float);
  float* ws_f_et = (float*)w;    w += B * C * sizeof(float);
  float* ws_f_gs = (float*)w;    w += B * C * sizeof(float);
  float* ws_f_gt = (float*)w;    w += B * C * sizeof(float);
  float* ws_soft_s = (float*)w;  w += B * NCLS * sizeof(float);
  float* ws_soft_t = (float*)w;  w += B * NCLS * sizeof(float);
  float* ws_wn_s = (float*)w;    w += B * sizeof(float);
  float* ws_wn_t = (float*)w;    w += B * sizeof(float);
  int* ws_nbr_s = (int*)w;       w += B * KNN_K * sizeof(int);
  int* ws_nbr_t = (int*)w;       w += B * KNN_K * sizeof(int);
  float* ws_pos = (float*)w;     w += 4 * B * sizeof(float);
  float* ws_partial = (float*)w; w += 4 * B * NCHUNK * sizeof(float);

  embed2_kernel<<<dim3(B / 4, 2), 256, 0, stream>>>(f_s, W_es, b_es, f_t, W_et,
                                                    b_et, ws_f_es, ws_f_et);

  knn_soft_kernel<<<dim3(B, 2), 128, 0, stream>>>(l_s, l_t, ws_soft_s,
                                                  ws_soft_t, ws_wn_s, ws_wn_t);

  knn_topk_kernel<<<dim3(B, 2), 256, 0, stream>>>(ws_soft_s, ws_wn_s, ws_nbr_s,
                                                  ws_soft_t, ws_wn_t, ws_nbr_t);

  gnn_pos_kernel<<<B, 256, 0, stream>>>(ws_f_es, ws_f_et, ws_nbr_s, ws_nbr_t,
                                        W_gs, b_gs, W_gt, b_gt, mem_l, mem_ab,
                                        idx, ws_f_gs, ws_f_gt, ws_pos);

  neg_partial_kernel<<<dim3(B, NCHUNK, 2), 256, 0, stream>>>(
      mem_l, mem_ab, cidx, ws_f_es, ws_f_et, ws_f_gs, ws_f_gt, ws_partial);

  loss_kernel<<<1, 256, 0, stream>>>(ws_partial, ws_pos, (float*)d_out);
}